// Round 2
// baseline (4025.183 us; speedup 1.0000x reference)
//
#include <hip/hip_runtime.h>

#define B_ROWS 131072
#define EDIM   256
#define N_E    1024
#define BM     64          // rows per block, lane <-> row
#define ZSTR   260         // LDS row stride in words (1040B: 8 lanes -> 8 distinct 16B slots)
#define GCODES 16          // codes per accumulator group
#define KCH    64          // k-chunk resident in VGPRs

#define OUT1 ((size_t)B_ROWS * EDIM)       // loss scalar
#define OUT2 (OUT1 + 1)                    // indices [B]
#define OUT3 (OUT2 + B_ROWS)               // perplexity scalar

// numpy pairwise sum of squares over 128 elements (8-accumulator unrolled,
// exact combine tree), no FMA contraction: matches np.sum(x*x) bit-exactly.
__device__ inline float pw128_sq(const float* p) {
    float r[8];
#pragma unroll
    for (int j = 0; j < 8; ++j) r[j] = __fmul_rn(p[j], p[j]);
    for (int i = 8; i < 128; i += 8) {
#pragma unroll
        for (int j = 0; j < 8; ++j)
            r[j] = __fadd_rn(r[j], __fmul_rn(p[i + j], p[i + j]));
    }
    float s01 = __fadd_rn(r[0], r[1]), s23 = __fadd_rn(r[2], r[3]);
    float s45 = __fadd_rn(r[4], r[5]), s67 = __fadd_rn(r[6], r[7]);
    return __fadd_rn(__fadd_rn(s01, s23), __fadd_rn(s45, s67));
}
__device__ inline float sumsq256(const float* p) {
    return __fadd_rn(pw128_sq(p), pw128_sq(p + 128));
}

__global__ void vq_esq(const float* __restrict__ emb, float* __restrict__ esq) {
    int n = blockIdx.x * 256 + threadIdx.x;
    if (n < N_E) esq[n] = sumsq256(emb + (size_t)n * EDIM);
}

__global__ __launch_bounds__(256, 2) void vq_main(
    const float* __restrict__ z, const float* __restrict__ emb,
    const float* __restrict__ esq, float* __restrict__ out,
    unsigned int* __restrict__ count, double* __restrict__ lossSum)
{
    __shared__ float  zt[BM * ZSTR];       // 66,560 B
    __shared__ float  wd[4][BM];
    __shared__ int    wn[4][BM];
    __shared__ int    rowbest[BM];
    __shared__ double red[256];

    const int tid  = threadIdx.x;
    const int blk  = blockIdx.x;
    const int wave = tid >> 6;
    const int lane = tid & 63;

    // ---- stage z tile [64][256] -> LDS (coalesced float4) ----
    const float4* zg = (const float4*)(z + (size_t)blk * BM * EDIM);
#pragma unroll
    for (int it = 0; it < 16; ++it) {
        int fidx = it * 256 + tid;          // 0..4095
        int m = fidx >> 6, k4 = fidx & 63;
        *(float4*)&zt[m * ZSTR + k4 * 4] = zg[fidx];
    }
    __syncthreads();

    // ---- per-lane zsq (row = lane), numpy-pairwise-exact, per-wave redundant ----
    float zsq = sumsq256(&zt[lane * ZSTR]);

    float bd = INFINITY;
    int   bn = 0;

    const int code0 = wave * 256;          // each wave owns 256 codes

    for (int g = 0; g < 256 / GCODES; ++g) {
        float acc[GCODES];
#pragma unroll
        for (int n = 0; n < GCODES; ++n) acc[n] = 0.f;

        const int gc = code0 + g * GCODES;

        for (int h = 0; h < EDIM / KCH; ++h) {
            // z chunk: LDS -> VGPR, per-lane distinct, conflict-free pattern
            float4 zc[KCH / 4];
#pragma unroll
            for (int j = 0; j < KCH / 4; ++j)
                zc[j] = *(const float4*)&zt[lane * ZSTR + h * KCH + j * 4];

#pragma unroll
            for (int n = 0; n < GCODES; ++n) {
                const float4* ep = (const float4*)(emb + (size_t)(gc + n) * EDIM + h * KCH);
#pragma unroll
                for (int j = 0; j < KCH / 4; ++j) {
                    float4 ev = ep[j];     // wave-uniform address: 1 txn, L2/L3-hot
                    acc[n] = __fmaf_rn(zc[j].x, ev.x, acc[n]);
                    acc[n] = __fmaf_rn(zc[j].y, ev.y, acc[n]);
                    acc[n] = __fmaf_rn(zc[j].z, ev.z, acc[n]);
                    acc[n] = __fmaf_rn(zc[j].w, ev.w, acc[n]);
                }
            }
        }

        // group tail: d = fl(fl(zsq+esq) - 2*dot), running argmin (codes ascending, strict <)
#pragma unroll
        for (int n4 = 0; n4 < GCODES / 4; ++n4) {
            float4 eq = *(const float4*)&esq[gc + n4 * 4];
            float eqa[4] = {eq.x, eq.y, eq.z, eq.w};
#pragma unroll
            for (int q = 0; q < 4; ++q) {
                int n = n4 * 4 + q;
                float d = __fsub_rn(__fadd_rn(zsq, eqa[q]), 2.0f * acc[n]);
                if (d < bd) { bd = d; bn = gc + n; }
            }
        }
    }

    // ---- cross-wave merge (each wave has the best over its 256 codes) ----
    wd[wave][lane] = bd;
    wn[wave][lane] = bn;
    __syncthreads();
    if (tid < BM) {
        float d = wd[0][tid]; int n = wn[0][tid];
#pragma unroll
        for (int w = 1; w < 4; ++w) {
            float dw = wd[w][tid]; int nw = wn[w][tid];
            if (dw < d) { d = dw; n = nw; }   // strict <: lower wave = lower codes wins ties
        }
        rowbest[tid] = n;
    }
    __syncthreads();

    // ---- output: gather z_q, STE, loss partial, index, histogram ----
    const int row = tid >> 2;              // 0..63
    const int q   = tid & 3;               // 4 threads per row
    const size_t grow = (size_t)blk * BM + row;
    const int bnr = rowbest[row];
    const float4* ebr = (const float4*)(emb + (size_t)bnr * EDIM);
    float4* outr = (float4*)(out + grow * EDIM);
    double lacc = 0.0;
#pragma unroll
    for (int i = 0; i < 16; ++i) {
        int k4 = q + i * 4;
        float4 zv = *(const float4*)&zt[row * ZSTR + k4 * 4];
        float4 ev = ebr[k4];
        float4 o;
        float s;
        s = __fsub_rn(ev.x, zv.x); o.x = __fadd_rn(zv.x, s); lacc += (double)__fmul_rn(s, s);
        s = __fsub_rn(ev.y, zv.y); o.y = __fadd_rn(zv.y, s); lacc += (double)__fmul_rn(s, s);
        s = __fsub_rn(ev.z, zv.z); o.z = __fadd_rn(zv.z, s); lacc += (double)__fmul_rn(s, s);
        s = __fsub_rn(ev.w, zv.w); o.w = __fadd_rn(zv.w, s); lacc += (double)__fmul_rn(s, s);
        outr[k4] = o;
    }
    if (q == 0) {
        out[OUT2 + grow] = (float)bnr;
        atomicAdd(&count[bnr], 1u);
    }
    red[tid] = lacc;
    __syncthreads();
    for (int s = 128; s > 0; s >>= 1) {
        if (tid < s) red[tid] += red[tid + s];
        __syncthreads();
    }
    if (tid == 0) atomicAdd(lossSum, red[0]);
}

__global__ void vq_finalize(const unsigned int* __restrict__ count,
                            const double* __restrict__ lossSum,
                            float* __restrict__ out)
{
    __shared__ double red[1024];
    int t = threadIdx.x;
    double em = (double)count[t] * (1.0 / 131072.0);
    red[t] = em * log(em + 1e-10);
    __syncthreads();
    for (int s = 512; s > 0; s >>= 1) {
        if (t < s) red[t] += red[t + s];
        __syncthreads();
    }
    if (t == 0) {
        out[OUT3] = (float)exp(-red[0]);
        double m = lossSum[0] * (1.0 / 33554432.0);   // mean over B*EDIM
        out[OUT1] = (float)(1.25 * m);                 // mean + BETA*mean
    }
}

extern "C" void kernel_launch(void* const* d_in, const int* in_sizes, int n_in,
                              void* d_out, int out_size, void* d_ws, size_t ws_size,
                              hipStream_t stream) {
    const float* z   = (const float*)d_in[0];
    const float* emb = (const float*)d_in[1];
    float* out = (float*)d_out;

    unsigned int* count = (unsigned int*)d_ws;                    // 1024 * 4 B
    double* lossSum     = (double*)((char*)d_ws + 4096);          // 8 B
    float*  esq         = (float*)((char*)d_ws + 4608);           // 1024 * 4 B

    hipMemsetAsync(d_ws, 0, 4104, stream);
    vq_esq<<<4, 256, 0, stream>>>(emb, esq);
    vq_main<<<B_ROWS / BM, 256, 0, stream>>>(z, emb, esq, out, count, lossSum);
    vq_finalize<<<1, 1024, 0, stream>>>(count, lossSum, out);
}

// Round 3
// 959.317 us; speedup vs baseline: 4.1959x; 4.1959x over previous
//
#include <hip/hip_runtime.h>

typedef __attribute__((ext_vector_type(8))) __bf16 bf16x8;
typedef __attribute__((ext_vector_type(4))) float f32x4;
typedef __attribute__((ext_vector_type(8))) unsigned short u16x8;

#define B_ROWS 131072
#define EDIM   256
#define N_E    1024
#define BMR    64          // rows per block
#define CHUNKS 32          // 32 chunks x 32 codes
#define CAP    16

#define OUT1 ((size_t)B_ROWS * EDIM)       // loss scalar
#define OUT2 (OUT1 + 1)                    // indices [B]
#define OUT3 (OUT2 + B_ROWS)               // perplexity scalar

// ws layout
#define WS_EMB16 0          // 1024*256 ushort = 524288 B
#define WS_ESQ   524288     // 1024 float
#define WS_COUNT 528384     // 1024 uint
#define WS_LOSS  532480     // 1 double

__device__ __forceinline__ unsigned short f2bf(float f) {   // RN to bf16
    unsigned u = __float_as_uint(f);
    return (unsigned short)((u + 0x7FFFu + ((u >> 16) & 1u)) >> 16);
}
__device__ __forceinline__ unsigned encf(float f) {          // order-preserving
    unsigned u = __float_as_uint(f);
    return u ^ (unsigned)(((int)u >> 31) | 0x80000000);
}
__device__ __forceinline__ float decf(unsigned x) {
    return (x & 0x80000000u) ? __uint_as_float(x ^ 0x80000000u)
                             : __uint_as_float(~x);
}

// numpy pairwise sum-of-squares over 128 elems (exact tree, no contraction)
__device__ inline float pw128_sq(const float* p) {
    float r[8];
#pragma unroll
    for (int j = 0; j < 8; ++j) r[j] = __fmul_rn(p[j], p[j]);
    for (int i = 8; i < 128; i += 8) {
#pragma unroll
        for (int j = 0; j < 8; ++j)
            r[j] = __fadd_rn(r[j], __fmul_rn(p[i + j], p[i + j]));
    }
    float s01 = __fadd_rn(r[0], r[1]), s23 = __fadd_rn(r[2], r[3]);
    float s45 = __fadd_rn(r[4], r[5]), s67 = __fadd_rn(r[6], r[7]);
    return __fadd_rn(__fadd_rn(s01, s23), __fadd_rn(s45, s67));
}

// exact fp32 distance, bit-identical to the verified rounds-1/2 chain
__device__ inline float exact_d(const float* zp, const float* ep, float zsq, float eq) {
    const float4* z4 = (const float4*)zp;
    const float4* e4 = (const float4*)ep;
    float acc = 0.f;
#pragma unroll 8
    for (int k = 0; k < 64; ++k) {
        float4 a = z4[k], b = e4[k];
        acc = __fmaf_rn(a.x, b.x, acc);
        acc = __fmaf_rn(a.y, b.y, acc);
        acc = __fmaf_rn(a.z, b.z, acc);
        acc = __fmaf_rn(a.w, b.w, acc);
    }
    return __fsub_rn(__fadd_rn(zsq, eq), 2.0f * acc);
}

__global__ void prep_emb(const float* __restrict__ emb,
                         unsigned short* __restrict__ emb16,
                         float* __restrict__ esqg)
{
    int n = blockIdx.x, t = threadIdx.x;          // 1024 blocks x 64 threads
    const float4 v = ((const float4*)(emb + (size_t)n * EDIM))[t];
    ushort4 o = { f2bf(v.x), f2bf(v.y), f2bf(v.z), f2bf(v.w) };
    ((ushort4*)(emb16 + (size_t)n * EDIM))[t] = o;
    if (t < 2) {
        float h = pw128_sq(emb + (size_t)n * EDIM + 128 * t);
        float ho = __shfl_xor(h, 1);
        if (t == 0) esqg[n] = __fadd_rn(h, ho);
    }
}

__global__ __launch_bounds__(256, 2) void vq_main(
    const float* __restrict__ z, const float* __restrict__ emb,
    const unsigned short* __restrict__ emb16, const float* __restrict__ esqg,
    float* __restrict__ out, unsigned int* __restrict__ count,
    double* __restrict__ lossSum)
{
    __shared__ unsigned short zt[BMR * EDIM];        // 32 KB, XOR-swizzled granules
    __shared__ unsigned short et[2][32 * EDIM];      // 2 x 16 KB
    __shared__ float esq_s[N_E];
    __shared__ float zsq_s[BMR], S_s[BMR];
    __shared__ unsigned smin[BMR], cnt[BMR];
    __shared__ int list[BMR][CAP];
    __shared__ int rowbest[BMR];
    __shared__ double red[256];

    const int tid  = threadIdx.x;
    const int blk  = blockIdx.x;
    const int lane = tid & 63;
    const int w    = tid >> 6;
    const int col  = lane & 15;
    const int quad = lane >> 4;
    const int nt   = w >> 1;       // n-tile within chunk (0/1)
    const int mh   = w & 1;        // row-half (rows 32*mh..+32)

    // ---- stage z -> LDS bf16 (XOR-swizzled), coalesced ----
#pragma unroll
    for (int rd = 0; rd < 8; ++rd) {
        int G = rd * 256 + tid;                      // granule 0..2047
        int row = G >> 5;
        int gl  = (G & 31) ^ (row & 7);
        const float4* s4 = (const float4*)(z + ((size_t)blk * BMR + row) * EDIM + gl * 8);
        float4 f0 = s4[0], f1 = s4[1];
        u16x8 v = { f2bf(f0.x), f2bf(f0.y), f2bf(f0.z), f2bf(f0.w),
                    f2bf(f1.x), f2bf(f1.y), f2bf(f1.z), f2bf(f1.w) };
        *(u16x8*)&zt[G * 8] = v;
    }
    // ---- stage e chunk 0 ----
#pragma unroll
    for (int r2 = 0; r2 < 4; ++r2) {
        int G2 = r2 * 256 + tid;
        int erow = G2 >> 5;
        int gl = (G2 & 31) ^ (erow & 7);
        *(u16x8*)&et[0][G2 * 8] = *(const u16x8*)&emb16[(size_t)erow * EDIM + gl * 8];
    }
    for (int i = tid; i < N_E; i += 256) esq_s[i] = esqg[i];
    if (tid < BMR) { smin[tid] = 0xFFFFFFFFu; cnt[tid] = 0u; }

    // ---- exact zsq (np-pairwise) + S = sum|z| ----
    if (tid < 128) {
        int row = tid >> 1, half = tid & 1;
        const float* p = z + ((size_t)blk * BMR + row) * EDIM + half * 128;
        float h = pw128_sq(p);
        float sa = 0.f;
        for (int k = 0; k < 128; ++k) sa += fabsf(p[k]);
        float ho = __shfl_xor(h, 1);
        float so = __shfl_xor(sa, 1);
        if (half == 0) {
            zsq_s[row] = __fadd_rn(h, ho);
            S_s[row]   = (sa + so) * 1.001f;
        }
    }
    __syncthreads();

    // ---- per-lane constants: margins, a-fragments (z) resident in VGPRs ----
    float Mrow[2][4];
#pragma unroll
    for (int mti = 0; mti < 2; ++mti)
#pragma unroll
        for (int r = 0; r < 4; ++r) {
            int row = 32 * mh + 16 * mti + 4 * quad + r;
            Mrow[mti][r] = S_s[row] * (1.0f / 65536.0f) + 1e-3f;
        }
    bf16x8 afr[2][8];
#pragma unroll
    for (int mti = 0; mti < 2; ++mti) {
        int row = 32 * mh + 16 * mti + col;
#pragma unroll
        for (int ks = 0; ks < 8; ++ks) {
            int gl = ks * 4 + quad;
            afr[mti][ks] = *(const bf16x8*)&zt[row * EDIM + ((gl ^ (row & 7)) * 8)];
        }
    }
    float mhat[2][4];
#pragma unroll
    for (int mti = 0; mti < 2; ++mti)
#pragma unroll
        for (int r = 0; r < 4; ++r) mhat[mti][r] = INFINITY;

    // ---- chunk loop: prefetch(c+1) || MFMA(c) || scores/append, 1 barrier ----
    for (int c = 0; c < CHUNKS; ++c) {
        u16x8 pf[4];
        const bool havepf = (c + 1 < CHUNKS);
        if (havepf) {
#pragma unroll
            for (int r2 = 0; r2 < 4; ++r2) {
                int G2 = r2 * 256 + tid;
                int erow = G2 >> 5;
                int gl = (G2 & 31) ^ (erow & 7);
                pf[r2] = *(const u16x8*)&emb16[((size_t)(c + 1) * 32 + erow) * EDIM + gl * 8];
            }
        }
        const unsigned short* eb = &et[c & 1][0];
        f32x4 acc0 = {0.f, 0.f, 0.f, 0.f}, acc1 = {0.f, 0.f, 0.f, 0.f};
        const int erow = nt * 16 + col;
#pragma unroll
        for (int ks = 0; ks < 8; ++ks) {
            bf16x8 b = *(const bf16x8*)&eb[erow * EDIM + (((ks * 4 + quad) ^ (erow & 7)) * 8)];
            acc0 = __builtin_amdgcn_mfma_f32_16x16x32_bf16(afr[0][ks], b, acc0, 0, 0, 0);
            acc1 = __builtin_amdgcn_mfma_f32_16x16x32_bf16(afr[1][ks], b, acc1, 0, 0, 0);
        }
        const int codeN = c * 32 + nt * 16 + col;
        const float eqv = esq_s[codeN];
        float s[2][4], cm[2][4];
#pragma unroll
        for (int r = 0; r < 4; ++r) {
            s[0][r] = __fmaf_rn(-2.0f, acc0[r], eqv);
            s[1][r] = __fmaf_rn(-2.0f, acc1[r], eqv);
            cm[0][r] = s[0][r]; cm[1][r] = s[1][r];
        }
#pragma unroll
        for (int mask = 1; mask <= 8; mask <<= 1)
#pragma unroll
            for (int mti = 0; mti < 2; ++mti)
#pragma unroll
                for (int r = 0; r < 4; ++r)
                    cm[mti][r] = fminf(cm[mti][r], __shfl_xor(cm[mti][r], mask));
#pragma unroll
        for (int mti = 0; mti < 2; ++mti)
#pragma unroll
            for (int r = 0; r < 4; ++r) {
                int row = 32 * mh + 16 * mti + 4 * quad + r;
                if (col == mti * 4 + r && cm[mti][r] < mhat[mti][r])
                    atomicMin(&smin[row], encf(cm[mti][r]));
                unsigned sv = *(volatile unsigned*)&smin[row];
                float mhv = fminf(fminf(mhat[mti][r], decf(sv)), cm[mti][r]);
                mhat[mti][r] = mhv;
                if (s[mti][r] <= mhv + Mrow[mti][r]) {
                    unsigned i = atomicAdd(&cnt[row], 1u);
                    if (i < CAP) list[row][i] = codeN;
                }
            }
        if (havepf) {
#pragma unroll
            for (int r2 = 0; r2 < 4; ++r2) {
                int G2 = r2 * 256 + tid;
                *(u16x8*)&et[(c + 1) & 1][G2 * 8] = pf[r2];
            }
        }
        __syncthreads();
    }

    // ---- exact rescore of candidates (4 lanes / row) ----
    {
        int row = tid >> 2, j = tid & 3;
        int cn = (int)cnt[row];
        unsigned long long bkey = ~0ull;
        const float* zrow = z + ((size_t)blk * BMR + row) * EDIM;
        float zq = zsq_s[row];
        if (cn <= CAP) {
            for (int i = j; i < cn; i += 4) {
                int n = list[row][i];
                float d = exact_d(zrow, emb + (size_t)n * EDIM, zq, esq_s[n]);
                unsigned long long key = ((unsigned long long)encf(d) << 32) | (unsigned)n;
                if (key < bkey) bkey = key;
            }
        }
#pragma unroll
        for (int m = 1; m <= 2; m <<= 1) {
            unsigned long long o = __shfl_xor(bkey, m);
            if (o < bkey) bkey = o;
        }
        if (j == 0) rowbest[row] = (cn <= CAP) ? (int)(bkey & 0xFFFFFFFFu) : -1;
    }
    __syncthreads();

    // ---- overflow rows: full exact scan, block-cooperative (rare) ----
    {
        unsigned long long* red64 = (unsigned long long*)red;
        for (int r = 0; r < BMR; ++r) {
            if (rowbest[r] != -1) continue;       // uniform branch
            const float* zr = z + ((size_t)blk * BMR + r) * EDIM;
            float zqr = zsq_s[r];
            unsigned long long k = ~0ull;
            for (int ci = 0; ci < 4; ++ci) {
                int n = tid + ci * 256;
                float d = exact_d(zr, emb + (size_t)n * EDIM, zqr, esq_s[n]);
                unsigned long long key = ((unsigned long long)encf(d) << 32) | (unsigned)n;
                if (key < k) k = key;
            }
            red64[tid] = k; __syncthreads();
            for (int sR = 128; sR > 0; sR >>= 1) {
                if (tid < sR && red64[tid + sR] < red64[tid]) red64[tid] = red64[tid + sR];
                __syncthreads();
            }
            if (tid == 0) rowbest[r] = (int)(red64[0] & 0xFFFFFFFFu);
            __syncthreads();
        }
    }
    __syncthreads();

    // ---- epilogue: gather z_q, STE, loss partial, index, histogram ----
    {
        const int row = tid >> 2, q = tid & 3;
        const size_t grow = (size_t)blk * BMR + row;
        const int bn = rowbest[row];
        const float4* zp4 = (const float4*)(z + grow * EDIM);
        const float4* ebr = (const float4*)(emb + (size_t)bn * EDIM);
        float4* outr = (float4*)(out + grow * EDIM);
        double lacc = 0.0;
#pragma unroll
        for (int i = 0; i < 16; ++i) {
            int k4 = q + i * 4;
            float4 zv = zp4[k4];
            float4 ev = ebr[k4];
            float4 o; float sd;
            sd = __fsub_rn(ev.x, zv.x); o.x = __fadd_rn(zv.x, sd); lacc += (double)__fmul_rn(sd, sd);
            sd = __fsub_rn(ev.y, zv.y); o.y = __fadd_rn(zv.y, sd); lacc += (double)__fmul_rn(sd, sd);
            sd = __fsub_rn(ev.z, zv.z); o.z = __fadd_rn(zv.z, sd); lacc += (double)__fmul_rn(sd, sd);
            sd = __fsub_rn(ev.w, zv.w); o.w = __fadd_rn(zv.w, sd); lacc += (double)__fmul_rn(sd, sd);
            outr[k4] = o;
        }
        if (q == 0) {
            out[OUT2 + grow] = (float)bn;
            atomicAdd(&count[bn], 1u);
        }
        red[tid] = lacc;
        __syncthreads();
        for (int sR = 128; sR > 0; sR >>= 1) {
            if (tid < sR) red[tid] += red[tid + sR];
            __syncthreads();
        }
        if (tid == 0) atomicAdd(lossSum, red[0]);
    }
}

__global__ void vq_finalize(const unsigned int* __restrict__ count,
                            const double* __restrict__ lossSum,
                            float* __restrict__ out)
{
    __shared__ double red[1024];
    int t = threadIdx.x;
    double em = (double)count[t] * (1.0 / 131072.0);
    red[t] = em * log(em + 1e-10);
    __syncthreads();
    for (int s = 512; s > 0; s >>= 1) {
        if (t < s) red[t] += red[t + s];
        __syncthreads();
    }
    if (t == 0) {
        out[OUT3] = (float)exp(-red[0]);
        double m = lossSum[0] * (1.0 / 33554432.0);
        out[OUT1] = (float)(1.25 * m);
    }
}

extern "C" void kernel_launch(void* const* d_in, const int* in_sizes, int n_in,
                              void* d_out, int out_size, void* d_ws, size_t ws_size,
                              hipStream_t stream) {
    const float* z   = (const float*)d_in[0];
    const float* emb = (const float*)d_in[1];
    float* out = (float*)d_out;

    unsigned short* emb16 = (unsigned short*)((char*)d_ws + WS_EMB16);
    float* esqg           = (float*)((char*)d_ws + WS_ESQ);
    unsigned int* count   = (unsigned int*)((char*)d_ws + WS_COUNT);
    double* lossSum       = (double*)((char*)d_ws + WS_LOSS);

    hipMemsetAsync((char*)d_ws + WS_COUNT, 0, 4104, stream);
    prep_emb<<<N_E, 64, 0, stream>>>(emb, emb16, esqg);
    vq_main<<<B_ROWS / BMR, 256, 0, stream>>>(z, emb, emb16, esqg, out, count, lossSum);
    vq_finalize<<<1, 1024, 0, stream>>>(count, lossSum, out);
}

// Round 4
// 356.604 us; speedup vs baseline: 11.2875x; 2.6901x over previous
//
#include <hip/hip_runtime.h>

typedef __attribute__((ext_vector_type(8))) __bf16 bf16x8;
typedef __attribute__((ext_vector_type(4))) float f32x4;
typedef __attribute__((ext_vector_type(8))) unsigned short u16x8;

#define B_ROWS 131072
#define EDIM   256
#define N_E    1024
#define BMR    64          // rows per block
#define CHUNKS 32          // 32 chunks x 32 codes
#define CAP    16

#define OUT1 ((size_t)B_ROWS * EDIM)       // loss scalar
#define OUT2 (OUT1 + 1)                    // indices [B]
#define OUT3 (OUT2 + B_ROWS)               // perplexity scalar

// ws layout
#define WS_EMB16 0          // 1024*256 ushort = 524288 B
#define WS_ESQ   524288     // 1024 float
#define WS_COUNT 528384     // 1024 uint
#define WS_LOSS  532480     // 1 double

__device__ __forceinline__ unsigned short f2bf(float f) {   // RN to bf16
    unsigned u = __float_as_uint(f);
    return (unsigned short)((u + 0x7FFFu + ((u >> 16) & 1u)) >> 16);
}
__device__ __forceinline__ unsigned encf(float f) {          // order-preserving
    unsigned u = __float_as_uint(f);
    return u ^ (unsigned)(((int)u >> 31) | 0x80000000);
}
__device__ __forceinline__ float decf(unsigned x) {
    return (x & 0x80000000u) ? __uint_as_float(x ^ 0x80000000u)
                             : __uint_as_float(~x);
}

// numpy pairwise sum-of-squares over 128 elems (exact tree, no contraction)
__device__ inline float pw128_sq(const float* p) {
    float r[8];
#pragma unroll
    for (int j = 0; j < 8; ++j) r[j] = __fmul_rn(p[j], p[j]);
    for (int i = 8; i < 128; i += 8) {
#pragma unroll
        for (int j = 0; j < 8; ++j)
            r[j] = __fadd_rn(r[j], __fmul_rn(p[i + j], p[i + j]));
    }
    float s01 = __fadd_rn(r[0], r[1]), s23 = __fadd_rn(r[2], r[3]);
    float s45 = __fadd_rn(r[4], r[5]), s67 = __fadd_rn(r[6], r[7]);
    return __fadd_rn(__fadd_rn(s01, s23), __fadd_rn(s45, s67));
}

// exact fp32 distance, bit-identical to the verified rounds-1..3 chain
__device__ inline float exact_d(const float* zp, const float* ep, float zsq, float eq) {
    const float4* z4 = (const float4*)zp;
    const float4* e4 = (const float4*)ep;
    float acc = 0.f;
#pragma unroll 8
    for (int k = 0; k < 64; ++k) {
        float4 a = z4[k], b = e4[k];
        acc = __fmaf_rn(a.x, b.x, acc);
        acc = __fmaf_rn(a.y, b.y, acc);
        acc = __fmaf_rn(a.z, b.z, acc);
        acc = __fmaf_rn(a.w, b.w, acc);
    }
    return __fsub_rn(__fadd_rn(zsq, eq), 2.0f * acc);
}

__global__ void prep_emb(const float* __restrict__ emb,
                         unsigned short* __restrict__ emb16,
                         float* __restrict__ esqg)
{
    int n = blockIdx.x, t = threadIdx.x;          // 1024 blocks x 64 threads
    const float4 v = ((const float4*)(emb + (size_t)n * EDIM))[t];
    ushort4 o = { f2bf(v.x), f2bf(v.y), f2bf(v.z), f2bf(v.w) };
    ((ushort4*)(emb16 + (size_t)n * EDIM))[t] = o;
    if (t < 2) {
        float h = pw128_sq(emb + (size_t)n * EDIM + 128 * t);
        float ho = __shfl_xor(h, 1);
        if (t == 0) esqg[n] = __fadd_rn(h, ho);
    }
}

__global__ __launch_bounds__(256, 2) void vq_main(
    const float* __restrict__ z, const float* __restrict__ emb,
    const unsigned short* __restrict__ emb16, const float* __restrict__ esqg,
    float* __restrict__ out, unsigned int* __restrict__ count,
    double* __restrict__ lossSum)
{
    __shared__ unsigned short zt[BMR * EDIM];        // 32 KB, XOR-swizzled granules
    __shared__ unsigned short et[2][32 * EDIM];      // 2 x 16 KB
    __shared__ float esq_s[N_E];
    __shared__ float zsq_s[BMR], S_s[BMR];
    __shared__ unsigned long long wd64[2][BMR];
    __shared__ float thrs[BMR];
    __shared__ unsigned cnt[BMR];
    __shared__ int list[BMR][CAP];
    __shared__ int rowbest[BMR];
    __shared__ double red[256];

    const int tid  = threadIdx.x;
    const int blk  = blockIdx.x;
    const int lane = tid & 63;
    const int w    = tid >> 6;
    const int col  = lane & 15;
    const int quad = lane >> 4;
    const int nt   = w >> 1;       // n-tile within chunk (0/1)
    const int mh   = w & 1;        // row-half (rows 32*mh..+32)

    // ---- stage z -> LDS bf16 (XOR-swizzled), coalesced ----
#pragma unroll
    for (int rd = 0; rd < 8; ++rd) {
        int G = rd * 256 + tid;                      // granule 0..2047
        int row = G >> 5;
        int gl  = (G & 31) ^ (row & 7);
        const float4* s4 = (const float4*)(z + ((size_t)blk * BMR + row) * EDIM + gl * 8);
        float4 f0 = s4[0], f1 = s4[1];
        u16x8 v = { f2bf(f0.x), f2bf(f0.y), f2bf(f0.z), f2bf(f0.w),
                    f2bf(f1.x), f2bf(f1.y), f2bf(f1.z), f2bf(f1.w) };
        *(u16x8*)&zt[G * 8] = v;
    }
    // ---- stage e chunk 0 ----
#pragma unroll
    for (int r2 = 0; r2 < 4; ++r2) {
        int G2 = r2 * 256 + tid;
        int erow = G2 >> 5;
        int gl = (G2 & 31) ^ (erow & 7);
        *(u16x8*)&et[0][G2 * 8] = *(const u16x8*)&emb16[(size_t)erow * EDIM + gl * 8];
    }
    for (int i = tid; i < N_E; i += 256) esq_s[i] = esqg[i];
    if (tid < BMR) cnt[tid] = 0u;

    // ---- exact zsq (np-pairwise) + S = sum|z| (any order; bound only) ----
    if (tid < 128) {
        int row = tid >> 1, half = tid & 1;
        const float* p = z + ((size_t)blk * BMR + row) * EDIM + half * 128;
        float h = pw128_sq(p);
        const float4* p4 = (const float4*)p;
        float4 sv = {0.f, 0.f, 0.f, 0.f};
#pragma unroll
        for (int jj = 0; jj < 32; ++jj) {
            float4 vv = p4[jj];
            sv.x += fabsf(vv.x); sv.y += fabsf(vv.y);
            sv.z += fabsf(vv.z); sv.w += fabsf(vv.w);
        }
        float sa = (sv.x + sv.y) + (sv.z + sv.w);
        float ho = __shfl_xor(h, 1);
        float so = __shfl_xor(sa, 1);
        if (half == 0) {
            zsq_s[row] = __fadd_rn(h, ho);
            S_s[row]   = (sa + so) * 1.001f;
        }
    }
    __syncthreads();

    // ---- per-lane constants: margins, rows, a-fragments resident in VGPRs ----
    int   rowid[2][4];
    float Mrow[2][4];
#pragma unroll
    for (int mti = 0; mti < 2; ++mti)
#pragma unroll
        for (int r = 0; r < 4; ++r) {
            int row = 32 * mh + 16 * mti + 4 * quad + r;
            rowid[mti][r] = row;
            Mrow[mti][r] = S_s[row] * (1.0f / 65536.0f) + 1e-3f;
        }
    bf16x8 afr[2][8];
#pragma unroll
    for (int mti = 0; mti < 2; ++mti) {
        int row = 32 * mh + 16 * mti + col;
#pragma unroll
        for (int ks = 0; ks < 8; ++ks) {
            int gl = ks * 4 + quad;
            afr[mti][ks] = *(const bf16x8*)&zt[row * EDIM + ((gl ^ (row & 7)) * 8)];
        }
    }

    const int erow = nt * 16 + col;

    // ================= PASS A: scores + register-only running min ==========
    float bd[2][4];
    int   bnn[2][4];
#pragma unroll
    for (int mti = 0; mti < 2; ++mti)
#pragma unroll
        for (int r = 0; r < 4; ++r) { bd[mti][r] = INFINITY; bnn[mti][r] = 0; }

    for (int c = 0; c < CHUNKS; ++c) {
        u16x8 pf[4];
        const bool havepf = (c + 1 < CHUNKS);
        if (havepf) {
#pragma unroll
            for (int r2 = 0; r2 < 4; ++r2) {
                int G2 = r2 * 256 + tid;
                int er = G2 >> 5;
                int gl = (G2 & 31) ^ (er & 7);
                pf[r2] = *(const u16x8*)&emb16[((size_t)(c + 1) * 32 + er) * EDIM + gl * 8];
            }
        }
        const unsigned short* eb = &et[c & 1][0];
        f32x4 acc0 = {0.f, 0.f, 0.f, 0.f}, acc1 = {0.f, 0.f, 0.f, 0.f};
#pragma unroll
        for (int ks = 0; ks < 8; ++ks) {
            bf16x8 b = *(const bf16x8*)&eb[erow * EDIM + (((ks * 4 + quad) ^ (erow & 7)) * 8)];
            acc0 = __builtin_amdgcn_mfma_f32_16x16x32_bf16(afr[0][ks], b, acc0, 0, 0, 0);
            acc1 = __builtin_amdgcn_mfma_f32_16x16x32_bf16(afr[1][ks], b, acc1, 0, 0, 0);
        }
        const int codeN = c * 32 + erow;
        const float eqv = esq_s[codeN];
#pragma unroll
        for (int r = 0; r < 4; ++r) {
            float s0 = __fmaf_rn(-2.0f, acc0[r], eqv);
            float s1 = __fmaf_rn(-2.0f, acc1[r], eqv);
            if (s0 < bd[0][r]) { bd[0][r] = s0; bnn[0][r] = codeN; }
            if (s1 < bd[1][r]) { bd[1][r] = s1; bnn[1][r] = codeN; }
        }
        if (havepf) {
#pragma unroll
            for (int r2 = 0; r2 < 4; ++r2) {
                int G2 = r2 * 256 + tid;
                *(u16x8*)&et[(c + 1) & 1][G2 * 8] = pf[r2];
            }
        }
        __syncthreads();
    }

    // ---- one-time cross-col reduce (lex min on (score, code)) ----
    unsigned long long key[2][4];
#pragma unroll
    for (int mti = 0; mti < 2; ++mti)
#pragma unroll
        for (int r = 0; r < 4; ++r)
            key[mti][r] = ((unsigned long long)encf(bd[mti][r]) << 32) | (unsigned)bnn[mti][r];
#pragma unroll
    for (int mask = 1; mask <= 8; mask <<= 1)
#pragma unroll
        for (int mti = 0; mti < 2; ++mti)
#pragma unroll
            for (int r = 0; r < 4; ++r) {
                unsigned long long o = __shfl_xor(key[mti][r], mask);
                if (o < key[mti][r]) key[mti][r] = o;
            }
    if (col == 0) {
#pragma unroll
        for (int mti = 0; mti < 2; ++mti)
#pragma unroll
            for (int r = 0; r < 4; ++r)
                wd64[nt][rowid[mti][r]] = key[mti][r];
    }
    __syncthreads();
    if (tid < BMR) {
        unsigned long long a = wd64[0][tid], b = wd64[1][tid];
        thrs[tid] = decf((unsigned)((a < b ? a : b) >> 32));
    }
    // restage e chunk 0 for pass B
#pragma unroll
    for (int r2 = 0; r2 < 4; ++r2) {
        int G2 = r2 * 256 + tid;
        int er = G2 >> 5;
        int gl = (G2 & 31) ^ (er & 7);
        *(u16x8*)&et[0][G2 * 8] = *(const u16x8*)&emb16[(size_t)er * EDIM + gl * 8];
    }
    __syncthreads();

    float thrM[2][4];
#pragma unroll
    for (int mti = 0; mti < 2; ++mti)
#pragma unroll
        for (int r = 0; r < 4; ++r)
            thrM[mti][r] = thrs[rowid[mti][r]] + Mrow[mti][r];

    // ================= PASS B: recompute scores, gather candidates =========
    for (int c = 0; c < CHUNKS; ++c) {
        u16x8 pf[4];
        const bool havepf = (c + 1 < CHUNKS);
        if (havepf) {
#pragma unroll
            for (int r2 = 0; r2 < 4; ++r2) {
                int G2 = r2 * 256 + tid;
                int er = G2 >> 5;
                int gl = (G2 & 31) ^ (er & 7);
                pf[r2] = *(const u16x8*)&emb16[((size_t)(c + 1) * 32 + er) * EDIM + gl * 8];
            }
        }
        const unsigned short* eb = &et[c & 1][0];
        f32x4 acc0 = {0.f, 0.f, 0.f, 0.f}, acc1 = {0.f, 0.f, 0.f, 0.f};
#pragma unroll
        for (int ks = 0; ks < 8; ++ks) {
            bf16x8 b = *(const bf16x8*)&eb[erow * EDIM + (((ks * 4 + quad) ^ (erow & 7)) * 8)];
            acc0 = __builtin_amdgcn_mfma_f32_16x16x32_bf16(afr[0][ks], b, acc0, 0, 0, 0);
            acc1 = __builtin_amdgcn_mfma_f32_16x16x32_bf16(afr[1][ks], b, acc1, 0, 0, 0);
        }
        const int codeN = c * 32 + erow;
        const float eqv = esq_s[codeN];
#pragma unroll
        for (int r = 0; r < 4; ++r) {
            float s0 = __fmaf_rn(-2.0f, acc0[r], eqv);
            float s1 = __fmaf_rn(-2.0f, acc1[r], eqv);
            if (s0 <= thrM[0][r]) {
                unsigned i = atomicAdd(&cnt[rowid[0][r]], 1u);
                if (i < CAP) list[rowid[0][r]][i] = codeN;
            }
            if (s1 <= thrM[1][r]) {
                unsigned i = atomicAdd(&cnt[rowid[1][r]], 1u);
                if (i < CAP) list[rowid[1][r]][i] = codeN;
            }
        }
        if (havepf) {
#pragma unroll
            for (int r2 = 0; r2 < 4; ++r2) {
                int G2 = r2 * 256 + tid;
                *(u16x8*)&et[(c + 1) & 1][G2 * 8] = pf[r2];
            }
        }
        __syncthreads();
    }

    // ---- exact rescore of candidates (4 lanes / row) ----
    {
        int row = tid >> 2, j = tid & 3;
        int cn = (int)cnt[row];
        unsigned long long bkey = ~0ull;
        const float* zrow = z + ((size_t)blk * BMR + row) * EDIM;
        float zq = zsq_s[row];
        if (cn <= CAP) {
            for (int i = j; i < cn; i += 4) {
                int n = list[row][i];
                float d = exact_d(zrow, emb + (size_t)n * EDIM, zq, esq_s[n]);
                unsigned long long k2 = ((unsigned long long)encf(d) << 32) | (unsigned)n;
                if (k2 < bkey) bkey = k2;
            }
        }
#pragma unroll
        for (int m = 1; m <= 2; m <<= 1) {
            unsigned long long o = __shfl_xor(bkey, m);
            if (o < bkey) bkey = o;
        }
        if (j == 0) rowbest[row] = (cn <= CAP) ? (int)(bkey & 0xFFFFFFFFu) : -1;
    }
    __syncthreads();

    // ---- overflow rows: full exact scan, block-cooperative (rare) ----
    {
        unsigned long long* red64 = (unsigned long long*)red;
        for (int r = 0; r < BMR; ++r) {
            if (rowbest[r] != -1) continue;       // uniform branch
            const float* zr = z + ((size_t)blk * BMR + r) * EDIM;
            float zqr = zsq_s[r];
            unsigned long long k = ~0ull;
            for (int ci = 0; ci < 4; ++ci) {
                int n = tid + ci * 256;
                float d = exact_d(zr, emb + (size_t)n * EDIM, zqr, esq_s[n]);
                unsigned long long k2 = ((unsigned long long)encf(d) << 32) | (unsigned)n;
                if (k2 < k) k = k2;
            }
            red64[tid] = k; __syncthreads();
            for (int sR = 128; sR > 0; sR >>= 1) {
                if (tid < sR && red64[tid + sR] < red64[tid]) red64[tid] = red64[tid + sR];
                __syncthreads();
            }
            if (tid == 0) rowbest[r] = (int)(red64[0] & 0xFFFFFFFFu);
            __syncthreads();
        }
    }
    __syncthreads();

    // ---- epilogue: gather z_q, STE, loss partial, index, histogram ----
    {
        const int row = tid >> 2, q = tid & 3;
        const size_t grow = (size_t)blk * BMR + row;
        const int bn = rowbest[row];
        const float4* zp4 = (const float4*)(z + grow * EDIM);
        const float4* ebr = (const float4*)(emb + (size_t)bn * EDIM);
        float4* outr = (float4*)(out + grow * EDIM);
        double lacc = 0.0;
#pragma unroll
        for (int i = 0; i < 16; ++i) {
            int k4 = q + i * 4;
            float4 zv = zp4[k4];
            float4 ev = ebr[k4];
            float4 o; float sd;
            sd = __fsub_rn(ev.x, zv.x); o.x = __fadd_rn(zv.x, sd); lacc += (double)__fmul_rn(sd, sd);
            sd = __fsub_rn(ev.y, zv.y); o.y = __fadd_rn(zv.y, sd); lacc += (double)__fmul_rn(sd, sd);
            sd = __fsub_rn(ev.z, zv.z); o.z = __fadd_rn(zv.z, sd); lacc += (double)__fmul_rn(sd, sd);
            sd = __fsub_rn(ev.w, zv.w); o.w = __fadd_rn(zv.w, sd); lacc += (double)__fmul_rn(sd, sd);
            outr[k4] = o;
        }
        if (q == 0) {
            out[OUT2 + grow] = (float)bn;
            atomicAdd(&count[bn], 1u);
        }
        red[tid] = lacc;
        __syncthreads();
        for (int sR = 128; sR > 0; sR >>= 1) {
            if (tid < sR) red[tid] += red[tid + sR];
            __syncthreads();
        }
        if (tid == 0) atomicAdd(lossSum, red[0]);
    }
}

__global__ void vq_finalize(const unsigned int* __restrict__ count,
                            const double* __restrict__ lossSum,
                            float* __restrict__ out)
{
    __shared__ double red[1024];
    int t = threadIdx.x;
    double em = (double)count[t] * (1.0 / 131072.0);
    red[t] = em * log(em + 1e-10);
    __syncthreads();
    for (int s = 512; s > 0; s >>= 1) {
        if (t < s) red[t] += red[t + s];
        __syncthreads();
    }
    if (t == 0) {
        out[OUT3] = (float)exp(-red[0]);
        double m = lossSum[0] * (1.0 / 33554432.0);
        out[OUT1] = (float)(1.25 * m);
    }
}

extern "C" void kernel_launch(void* const* d_in, const int* in_sizes, int n_in,
                              void* d_out, int out_size, void* d_ws, size_t ws_size,
                              hipStream_t stream) {
    const float* z   = (const float*)d_in[0];
    const float* emb = (const float*)d_in[1];
    float* out = (float*)d_out;

    unsigned short* emb16 = (unsigned short*)((char*)d_ws + WS_EMB16);
    float* esqg           = (float*)((char*)d_ws + WS_ESQ);
    unsigned int* count   = (unsigned int*)((char*)d_ws + WS_COUNT);
    double* lossSum       = (double*)((char*)d_ws + WS_LOSS);

    hipMemsetAsync((char*)d_ws + WS_COUNT, 0, 4104, stream);
    prep_emb<<<N_E, 64, 0, stream>>>(emb, emb16, esqg);
    vq_main<<<B_ROWS / BMR, 256, 0, stream>>>(z, emb, emb16, esqg, out, count, lossSum);
    vq_finalize<<<1, 1024, 0, stream>>>(count, lossSum, out);
}